// Round 13
// baseline (95.033 us; speedup 1.0000x reference)
//
#include <hip/hip_runtime.h>
#include <hip/hip_bf16.h>

#define M 256
#define NOUT 1024
#define KTOT 16384
#define RANK 16
#define NKC 32          // split-K factor
#define KCHUNK 512      // K per wave-job

typedef __attribute__((ext_vector_type(8)))  short bf16x8_t;
typedef __attribute__((ext_vector_type(4)))  float f32x4_t;
typedef __attribute__((ext_vector_type(16))) float f32x16_t;
typedef __attribute__((ext_vector_type(8)))  unsigned short u16x8_t;

static __device__ __forceinline__ unsigned short f2bf(float f) {
  unsigned u = __builtin_bit_cast(unsigned, f);
  u += 0x7FFFu + ((u >> 16) & 1u);   // round-to-nearest-even
  return (unsigned short)(u >> 16);
}
static __device__ __forceinline__ float bf2f(unsigned short h) {
  unsigned u = ((unsigned)h) << 16;
  return __builtin_bit_cast(float, u);
}
static __device__ __forceinline__ bf16x8_t cvt8f(float4 a, float4 b) {
  bf16x8_t r;
  r[0] = (short)f2bf(a.x); r[1] = (short)f2bf(a.y);
  r[2] = (short)f2bf(a.z); r[3] = (short)f2bf(a.w);
  r[4] = (short)f2bf(b.x); r[5] = (short)f2bf(b.y);
  r[6] = (short)f2bf(b.z); r[7] = (short)f2bf(b.w);
  return r;
}

// X stored FRAGMENT-MAJOR for the 32x32x16 B-operand (col=lane&31 -> b,
// k = (lane>>5)*8 + e):
//   element (b,k): t = k>>4 (16-k step), j = b>>5 (b-tile), l5 = (k>>3)&1
//   short-idx = (t*16 + j*2 + l5)*256 + (b&31)*8 + (k&7)
// A B-frag load for (t,j) is then 64 lanes x 16 B = 1 KB CONTIGUOUS.
__global__ __launch_bounds__(256) void build_x_kernel(
    const float* __restrict__ input, const float* __restrict__ coef,
    unsigned short* __restrict__ X)
{
  int idx = blockIdx.x * 256 + threadIdx.x;   // idx = b*1024 + i
  int b = idx >> 10, i = idx & 1023;
  float in = input[idx];
  const float* c = coef + b * RANK;
  u16x8_t lo, hi;                              // k = i*16 + r
  #pragma unroll
  for (int r = 0; r < 8; ++r) lo[r] = f2bf(in * c[r]);
  #pragma unroll
  for (int r = 0; r < 8; ++r) hi[r] = f2bf(in * c[8 + r]);
  // t = i; r<8 -> l5=0, r>=8 -> l5=1
  size_t base = (size_t)(i * 16 + (b >> 5) * 2) * 256 + (b & 31) * 8;
  *(u16x8_t*)(X + base)       = lo;
  *(u16x8_t*)(X + base + 256) = hi;
}

// out^T GEMM: part[kc][o][b] (bf16) = sum_{k in chunk kc} W[o,k] * X[b,k]
// via mfma_f32_32x32x16_bf16 (A = W-frag row->o, B = X-frag col->b).
//
// WAVE-AUTONOMOUS STREAMING (the hypothesis under test): each wave is one
// independent job (ot, kc) = 32 o-rows x 256 b x K=512. NO LDS, NO
// __syncthreads, NO inter-wave coupling of any kind -- structurally the
// same memory behavior as the 6.8 TB/s fill / m13 copy. W read exactly
// once grid-wide as direct A-frag register loads (32 rows x 64 B full
// cache lines per instr-pair); X read as 1 KB-contiguous fragment-major
// bursts from L2 (XCD-pinned kc). Fully unrolled 32-step body with no
// fences: the compiler software-pipelines loads as deep as VGPRs allow
// (4 waves/CU -> up to ~400 VGPR available).
__global__ __launch_bounds__(256, 1) void gemm_kernel(
    const unsigned short* __restrict__ X, const float* __restrict__ W,
    unsigned short* __restrict__ part)
{
  const int tid = threadIdx.x;                  // 0..255
  const int wv = tid >> 6, lane = tid & 63;
  const int l31 = lane & 31, l5 = lane >> 5;

  // XCD pinning: kc group fixed by lin&7 -> the 8 ot-blocks sharing a kc
  // X-slice (256 KB) land on one XCD's L2 (4 slices/XCD = 1 MB).
  const int lin = blockIdx.x;                   // 0..255
  const int kc = (lin & 7) * 4 + ((lin >> 3) & 3);
  const int ot = (lin >> 5) * 4 + wv;           // 0..31 (per wave)

  // W A-frag pointer: lane covers row ot*32+l31, 8 fp32 at k = t*16 + l5*8.
  const float* wp = W + (size_t)(ot * 32 + l31) * KTOT + kc * KCHUNK + l5 * 8;
  // X B-frag lane base: chunk kc = steps [kc*32, kc*32+32).
  const unsigned short* xp = X + (size_t)(kc * 32) * 16 * 256
                               + l5 * 256 + l31 * 8;

  f32x16_t acc[8];
  #pragma unroll
  for (int j = 0; j < 8; ++j) acc[j] = (f32x16_t)(0.0f);

  #pragma unroll
  for (int t = 0; t < 32; ++t) {               // 16 k per step
    float4 wa = *(const float4*)(wp + t * 16);
    float4 wb = *(const float4*)(wp + t * 16 + 4);
    bf16x8_t af = cvt8f(wa, wb);
    #pragma unroll
    for (int j = 0; j < 8; ++j) {              // 8 b-tiles of 32
      bf16x8_t xf = *(const bf16x8_t*)(xp + (size_t)(t * 16 + j * 2) * 256);
      acc[j] = __builtin_amdgcn_mfma_f32_32x32x16_bf16(af, xf, acc[j],
                                                       0, 0, 0);
    }
  }

  // ---- epilogue: D layout col(b)=l&31, row(o)=(q&3)+8*(q>>2)+4*l5 ----
  unsigned short* pp = part + (size_t)kc * (NOUT * 256);
  #pragma unroll
  for (int j = 0; j < 8; ++j) {
    #pragma unroll
    for (int q = 0; q < 16; ++q) {
      int oo = ot * 32 + (q & 3) + 8 * (q >> 2) + 4 * l5;
      pp[(size_t)oo * 256 + j * 32 + l31] = f2bf(acc[j][q]);
    }
  }
}

// out[b][o] = sum_kc bf2f(part[kc][o][b]) + sum_r bias[o][r]*coef[b][r]
// Block: 8 o-rows x 256 b; coalesced part reads; LDS transpose; coalesced
// out writes.
__global__ __launch_bounds__(256) void reduce_bias_kernel(
    const unsigned short* __restrict__ part, const float* __restrict__ bias,
    const float* __restrict__ coef, float* __restrict__ out)
{
  __shared__ float lds[8 * 256];
  const int t = threadIdx.x;
  const int o = blockIdx.x * 8 + (t >> 5);
  const int b8 = (t & 31) * 8;

  float s[8];
  #pragma unroll
  for (int j = 0; j < 8; ++j) s[j] = 0.f;

  #pragma unroll 8
  for (int kc = 0; kc < NKC; ++kc) {
    u16x8_t v = *(const u16x8_t*)(part + ((size_t)kc * NOUT + o) * 256 + b8);
    #pragma unroll
    for (int j = 0; j < 8; ++j) s[j] += bf2f(v[j]);
  }

  const f32x4_t* br = (const f32x4_t*)(bias + (size_t)o * RANK);
  f32x4_t b0 = br[0], b1 = br[1], b2 = br[2], b3 = br[3];
  #pragma unroll
  for (int j = 0; j < 8; ++j) {
    const f32x4_t* cr = (const f32x4_t*)(coef + (size_t)(b8 + j) * RANK);
    f32x4_t c0 = cr[0], c1 = cr[1], c2 = cr[2], c3 = cr[3];
    float bb = 0.f;
    #pragma unroll
    for (int e = 0; e < 4; ++e)
      bb += b0[e] * c0[e] + b1[e] * c1[e] + b2[e] * c2[e] + b3[e] * c3[e];
    s[j] += bb;
  }

  f32x4_t v0, v1;
  v0[0] = s[0]; v0[1] = s[1]; v0[2] = s[2]; v0[3] = s[3];
  v1[0] = s[4]; v1[1] = s[5]; v1[2] = s[6]; v1[3] = s[7];
  *(f32x4_t*)&lds[(t >> 5) * 256 + b8]     = v0;
  *(f32x4_t*)&lds[(t >> 5) * 256 + b8 + 4] = v1;
  __syncthreads();

  const int b = t;
  float g[8];
  #pragma unroll
  for (int j = 0; j < 8; ++j) g[j] = lds[j * 256 + b];
  float4* dst = (float4*)(out + (size_t)b * NOUT + blockIdx.x * 8);
  dst[0] = make_float4(g[0], g[1], g[2], g[3]);
  dst[1] = make_float4(g[4], g[5], g[6], g[7]);
}

extern "C" void kernel_launch(void* const* d_in, const int* in_sizes, int n_in,
                              void* d_out, int out_size, void* d_ws, size_t ws_size,
                              hipStream_t stream) {
  const float* input = (const float*)d_in[0];   // (256, 1024)
  const float* coef  = (const float*)d_in[1];   // (256, 16)
  const float* W     = (const float*)d_in[2];   // (1024, 1024, 16) -> (1024, 16384)
  const float* bias  = (const float*)d_in[3];   // (1024, 16)
  float* out = (float*)d_out;                   // (256, 1024)

  unsigned short* X    = (unsigned short*)d_ws;                               // 8 MiB bf16
  unsigned short* part = (unsigned short*)((char*)d_ws + (size_t)M * KTOT * 2); // 16 MiB bf16

  build_x_kernel<<<(M * 1024) / 256, 256, 0, stream>>>(input, coef, X);
  gemm_kernel<<<256, 256, 0, stream>>>(X, W, part);
  reduce_bias_kernel<<<NOUT / 8, 256, 0, stream>>>(part, bias, coef, out);
}

// Round 14
// 34.001 us; speedup vs baseline: 2.7950x; 2.7950x over previous
//
#include <hip/hip_runtime.h>
#include <hip/hip_bf16.h>

#define M 256
#define NOUT 1024
#define KTOT 16384
#define IN 1024
#define RANK 16
#define NKC 32          // split-K factor
#define KCHUNK 512      // K per block (32 i-values)
#define NPH 16          // phases per block (BK=32 -> 2 k-steps/phase)

typedef __attribute__((ext_vector_type(8)))  short bf16x8_t;
typedef __attribute__((ext_vector_type(4)))  float f32x4_t;
typedef __attribute__((ext_vector_type(16))) float f32x16_t;
typedef __attribute__((ext_vector_type(8)))  unsigned short u16x8_t;
typedef __attribute__((ext_vector_type(4)))  unsigned short u16x4_t;

static __device__ __forceinline__ unsigned short f2bf(float f) {
  unsigned u = __builtin_bit_cast(unsigned, f);
  u += 0x7FFFu + ((u >> 16) & 1u);   // round-to-nearest-even
  return (unsigned short)(u >> 16);
}
static __device__ __forceinline__ float bf2f(unsigned short h) {
  unsigned u = ((unsigned)h) << 16;
  return __builtin_bit_cast(float, u);
}
// fp32x4 -> bf16x4 ds_write piece (function args dodge the ##-paste bug)
static __device__ __forceinline__ void dsw4(unsigned short* dst, float4 v) {
  u16x4_t h;
  h[0] = f2bf(v.x); h[1] = f2bf(v.y); h[2] = f2bf(v.z); h[3] = f2bf(v.w);
  *(u16x4_t*)dst = h;
}

// GEMM, X NEVER MATERIALIZED: part[kc][b][o] (bf16) =
//   sum_{k in chunk kc} X[b,k] * W[o,k],  X[b,16i+r] = input[b,i]*coef[b,r]
// via mfma_f32_32x32x16_bf16, A = X-frag (row=l&31 -> b, k=(l>>5)*8+e),
// B = W-frag (col=l&31 -> o). A 16-k window = ONE i: A-frag is built in
// registers as input[b,i] (LDS scalar) * coef[b, l5*8..+8] (preloaded
// regs) -- no X stream exists. Block: 256 b x 64 o x K=512; 512 threads
// (8 waves = 4 b-quads x 2 o-halves, wave tile 64b x 32o). Grid 512 =
// 16 ot x 32 kc -> 2 blocks/CU (41 KB LDS). Per phase (BK=32): stage W
// 8 KB global->reg->bf16 ds_write (fragment-major -> conflict-free b128
// fragment reads), distance-2 named prefetch; ONE barrier per phase.
// VMEM traffic: W 64 MB + input 16 MB + part 32 MB ~= 112 MB total.
__global__ __launch_bounds__(512, 2) void gemm_kernel(
    const float* __restrict__ input, const float* __restrict__ coef,
    const float* __restrict__ W, unsigned short* __restrict__ part)
{
  __shared__ float          in_lds[256 * 33];    // 33 KB, pad 33 -> conflict-free
  __shared__ __align__(16) unsigned short Ws[2][2048];  // 2 x 4 KB frag-major bf16

  const int tid = threadIdx.x;                  // 0..511
  const int wid = tid >> 6, lane = tid & 63;
  const int l31 = lane & 31, l5 = lane >> 5;
  const int bq = wid >> 1, oc = wid & 1;        // wave: b-base bq*64, o-half oc*32
  const int bbase = bq * 64;

  // XCD swizzle (R6-proven bijective for 512): 8 ot-groups per XCD share kc.
  const int lin = blockIdx.y * 16 + blockIdx.x;
  const int swb = (lin & 7) * 64 + (lin >> 3);
  const int ot = swb & 15, kc = swb >> 4;

  const int o0 = ot * 64;
  const int kb0 = kc * KCHUNK;
  const int i0 = kc * 32;                       // 32 i-values per block

  f32x16_t acc0 = (f32x16_t)(0.0f), acc1 = (f32x16_t)(0.0f);

  // ---- prologue A: input slice [256 b][32 i] -> padded LDS (stride 33) ----
  {
    int b = tid >> 1, half = tid & 1;
    const float* src = input + (size_t)b * IN + i0 + half * 16;
    float* dst = in_lds + b * 33 + half * 16;
    #pragma unroll
    for (int j = 0; j < 16; ++j) dst[j] = src[j];   // b32 writes (align-safe)
  }

  // coef preload: frag0 b = bbase+l31, frag1 b = bbase+32+l31; r = l5*8+e
  float c0[8], c1[8];
  {
    const float* cp0 = coef + (size_t)(bbase + l31) * RANK + l5 * 8;
    const float* cp1 = coef + (size_t)(bbase + 32 + l31) * RANK + l5 * 8;
    #pragma unroll
    for (int e = 0; e < 8; ++e) { c0[e] = cp0[e]; c1[e] = cp1[e]; }
  }

  // W stage coords: thread q covers float4 = 4 k of row o = q>>3 at
  // k-off (q&7)*4 within the 32-k phase window. Frag-major dest:
  // group g = (koff>>3) = (q&7)>>1, half = (koff>>2)&1 = q&1:
  // byte = (g*64 + o)*16 + half*8.
  const int wo = tid >> 3, wk4 = (tid & 7) * 4;
  const float* wgp = W + (size_t)(o0 + wo) * KTOT + kb0 + wk4;
  const int wdst = ((((tid & 7) >> 1) * 64 + wo) * 8 + (tid & 1) * 4);  // shorts

  float4 wA, wB;    // distance-2 named prefetch sets (even/odd phases)

  #define LOADW(S, P) { w##S = *(const float4*)(wgp + (P) * 32); }
  #define DSW(S, BUF) dsw4(&Ws[BUF][wdst], w##S);

  #define KSTEP(TL, BUF)                                                     \
    {                                                                        \
      int i = (TL);                                                          \
      float in0 = in_lds[(bbase + l31) * 33 + i];                            \
      float in1 = in_lds[(bbase + 32 + l31) * 33 + i];                       \
      bf16x8_t af0, af1;                                                     \
      _Pragma("unroll")                                                      \
      for (int e = 0; e < 8; ++e) {                                          \
        af0[e] = (short)f2bf(in0 * c0[e]);                                   \
        af1[e] = (short)f2bf(in1 * c1[e]);                                   \
      }                                                                      \
      bf16x8_t bf = *(const bf16x8_t*)                                       \
          &Ws[BUF][((((TL) & 1) * 2 + l5) * 64 + oc * 32 + l31) * 8];        \
      __builtin_amdgcn_s_setprio(1);                                         \
      acc0 = __builtin_amdgcn_mfma_f32_32x32x16_bf16(af0, bf, acc0, 0, 0, 0);\
      acc1 = __builtin_amdgcn_mfma_f32_32x32x16_bf16(af1, bf, acc1, 0, 0, 0);\
      __builtin_amdgcn_s_setprio(0);                                         \
    }

  // phase p: [LOADW(p+2)] ; compute 2 k-steps from Ws[p&1] ; [DSW(p+1)] ; bar
  #define PHASE(P, SC, SN, DOL)                                              \
    if (DOL) { LOADW(SC, (P) + 2) }                                          \
    KSTEP((P) * 2,     (P) & 1)                                              \
    KSTEP((P) * 2 + 1, (P) & 1)                                              \
    if ((P) + 1 < NPH) { DSW(SN, ((P) + 1) & 1) }                            \
    __syncthreads();

  // ---- prologue B: W phases 0,1 in flight; write phase 0 ----
  LOADW(A, 0)
  LOADW(B, 1)
  DSW(A, 0)
  __syncthreads();

  PHASE(0,  A, B, 1)  PHASE(1,  B, A, 1)  PHASE(2,  A, B, 1)  PHASE(3,  B, A, 1)
  PHASE(4,  A, B, 1)  PHASE(5,  B, A, 1)  PHASE(6,  A, B, 1)  PHASE(7,  B, A, 1)
  PHASE(8,  A, B, 1)  PHASE(9,  B, A, 1)  PHASE(10, A, B, 1)  PHASE(11, B, A, 1)
  PHASE(12, A, B, 1)  PHASE(13, B, A, 1)  PHASE(14, A, B, 0)  PHASE(15, B, A, 0)

  // ---- epilogue: D row(b-part)=(q&3)+8*(q>>2)+4*l5, col(o)=l31 ----
  unsigned short* pp = part + (size_t)kc * (M * NOUT);
  #pragma unroll
  for (int q = 0; q < 16; ++q) {
    int brow = bbase + (q & 3) + 8 * (q >> 2) + 4 * l5;
    int ocol = o0 + oc * 32 + l31;
    pp[(size_t)brow * NOUT + ocol]        = f2bf(acc0[q]);
    pp[(size_t)(brow + 32) * NOUT + ocol] = f2bf(acc1[q]);
  }
  #undef LOADW
  #undef DSW
  #undef KSTEP
  #undef PHASE
}

// out[b][o] = sum_kc bf2f(part[kc][b][o]) + sum_r bias[o][r]*coef[b][r]
__global__ __launch_bounds__(256) void reduce_bias_kernel(
    const unsigned short* __restrict__ part, const float* __restrict__ bias,
    const float* __restrict__ coef, float* __restrict__ out)
{
  int t = blockIdx.x * 256 + threadIdx.x;
  int idx8 = t * 8;                       // 8 consecutive outputs, same b
  int b = idx8 >> 10, o = idx8 & 1023;

  float s[8];
  #pragma unroll
  for (int j = 0; j < 8; ++j) s[j] = 0.f;

  #pragma unroll
  for (int c = 0; c < NKC; ++c) {
    u16x8_t v = *(const u16x8_t*)(part + (size_t)c * (M * NOUT) + idx8);
    #pragma unroll
    for (int j = 0; j < 8; ++j) s[j] += bf2f(v[j]);
  }

  const f32x4_t* cr = (const f32x4_t*)(coef + (size_t)b * RANK);
  f32x4_t c0 = cr[0], c1 = cr[1], c2 = cr[2], c3 = cr[3];
  #pragma unroll
  for (int j = 0; j < 8; ++j) {
    const f32x4_t* br = (const f32x4_t*)(bias + (size_t)(o + j) * RANK);
    f32x4_t b0 = br[0], b1 = br[1], b2 = br[2], b3 = br[3];
    float bb = 0.f;
    #pragma unroll
    for (int e = 0; e < 4; ++e)
      bb += b0[e] * c0[e] + b1[e] * c1[e] + b2[e] * c2[e] + b3[e] * c3[e];
    s[j] += bb;
  }
  float4* dst = (float4*)(out + idx8);
  dst[0] = make_float4(s[0], s[1], s[2], s[3]);
  dst[1] = make_float4(s[4], s[5], s[6], s[7]);
}

extern "C" void kernel_launch(void* const* d_in, const int* in_sizes, int n_in,
                              void* d_out, int out_size, void* d_ws, size_t ws_size,
                              hipStream_t stream) {
  const float* input = (const float*)d_in[0];   // (256, 1024)
  const float* coef  = (const float*)d_in[1];   // (256, 16)
  const float* W     = (const float*)d_in[2];   // (1024, 1024, 16) -> (1024, 16384)
  const float* bias  = (const float*)d_in[3];   // (1024, 16)
  float* out = (float*)d_out;                   // (256, 1024)

  unsigned short* part = (unsigned short*)d_ws;   // 16 MiB bf16 partials

  gemm_kernel<<<dim3(16, 32), 512, 0, stream>>>(input, coef, W, part);
  reduce_bias_kernel<<<(M * NOUT) / (256 * 8), 256, 0, stream>>>(part, bias, coef, out);
}

// Round 15
// 31.214 us; speedup vs baseline: 3.0445x; 1.0893x over previous
//
#include <hip/hip_runtime.h>
#include <hip/hip_bf16.h>

#define M 256
#define NOUT 1024
#define KTOT 16384
#define IN 1024
#define RANK 16
#define NKC 32          // split-K factor
#define KCHUNK 512      // K per block (32 i-values)
#define NPH 8           // phases per block (BK=64 -> 4 k-steps/phase)

typedef __attribute__((ext_vector_type(8)))  short bf16x8_t;
typedef __attribute__((ext_vector_type(4)))  float f32x4_t;
typedef __attribute__((ext_vector_type(16))) float f32x16_t;
typedef __attribute__((ext_vector_type(8)))  unsigned short u16x8_t;

static __device__ __forceinline__ unsigned short f2bf(float f) {
  unsigned u = __builtin_bit_cast(unsigned, f);
  u += 0x7FFFu + ((u >> 16) & 1u);   // round-to-nearest-even
  return (unsigned short)(u >> 16);
}
static __device__ __forceinline__ float bf2f(unsigned short h) {
  unsigned u = ((unsigned)h) << 16;
  return __builtin_bit_cast(float, u);
}
// single-instruction packed fp32x2 -> bf16x2 (the 5-op manual f2bf was the
// R14 VALU bottleneck; no builtin exists on gfx950 -> inline asm)
static __device__ __forceinline__ unsigned cvtpk1(float lo, float hi) {
  unsigned r;
  asm("v_cvt_pk_bf16_f32 %0, %1, %2" : "=v"(r) : "v"(lo), "v"(hi));
  return r;
}
// A-frag build: 8 products s*c[e] -> bf16x8 via 4 cvt_pk
static __device__ __forceinline__ bf16x8_t mulcvt8(float s, const float* c) {
  union { bf16x8_t v; unsigned u[4]; } r;
  #pragma unroll
  for (int e = 0; e < 4; ++e)
    r.u[e] = cvtpk1(s * c[2 * e], s * c[2 * e + 1]);
  return r.v;
}
// fp32x4 -> bf16x4 -> one 8 B LDS store (2 cvt_pk)
static __device__ __forceinline__ void dsw4pk(unsigned short* dst, float4 v) {
  unsigned a = cvtpk1(v.x, v.y), b = cvtpk1(v.z, v.w);
  unsigned long long q = ((unsigned long long)b << 32) | (unsigned long long)a;
  *(unsigned long long*)dst = q;   // 8-B aligned by construction
}

// GEMM, X NEVER MATERIALIZED: part[kc][b][o] (bf16) =
//   sum_{k in chunk kc} X[b,k] * W[o,k],  X[b,16i+r] = input[b,i]*coef[b,r]
// via mfma_f32_32x32x16_bf16, A = X-frag (row=l&31 -> b, k=(l>>5)*8+e)
// built IN REGISTERS from input (LDS scalar) x coef (regs); B = W-frag
// (col=l&31 -> o) from fragment-major bf16 LDS (conflict-free b128 reads).
// Block: 256 b x 64 o x K=512; 512 threads (8 waves = 4 b-quads x 2
// o-halves). Grid 512 = 16 ot x 32 kc -> 2 blocks/CU (49 KB LDS).
// Per phase (BK=64): W 16 KB global->reg->cvt_pk->ds_write; distance-2
// named prefetch. Barriers are RAW (lgkmcnt(0) + s_barrier only): all
// VMEM targets are registers, so no vmcnt drain -- prefetch stays in
// flight across barriers (the R14 killer). VMEM: W 64 + input 16 = 80 MB.
__global__ __launch_bounds__(512, 4) void gemm_kernel(
    const float* __restrict__ input, const float* __restrict__ coef,
    const float* __restrict__ W, unsigned short* __restrict__ part)
{
  __shared__ float in_lds[256 * 33];                    // 33 KB, pad -> 2-way max
  __shared__ __align__(16) unsigned short Ws[2][4096];  // 2 x 8 KB frag-major

  const int tid = threadIdx.x;                  // 0..511
  const int wid = tid >> 6, lane = tid & 63;
  const int l31 = lane & 31, l5 = lane >> 5;
  const int bq = wid >> 1, oc = wid & 1;        // wave: b-base bq*64, o-half oc*32
  const int bbase = bq * 64;

  // XCD swizzle (bijective for 512): 8 ot-groups per XCD share kc slices.
  const int lin = blockIdx.y * 16 + blockIdx.x;
  const int swb = (lin & 7) * 64 + (lin >> 3);
  const int ot = swb & 15, kc = swb >> 4;

  const int o0 = ot * 64;
  const int kb0 = kc * KCHUNK;
  const int i0 = kc * 32;                       // 32 i-values per block

  f32x16_t acc0 = (f32x16_t)(0.0f), acc1 = (f32x16_t)(0.0f);

  // ---- prologue A: input slice [256 b][32 i] -> padded LDS (stride 33) ----
  {
    int b = tid >> 1, half = tid & 1;
    const float* src = input + (size_t)b * IN + i0 + half * 16;
    float* dst = in_lds + b * 33 + half * 16;
    #pragma unroll
    for (int j = 0; j < 16; ++j) dst[j] = src[j];   // 1 line fetch + L1 hits
  }

  // coef preload: frag0 b = bbase+l31, frag1 b = bbase+32+l31; r = l5*8+e
  float c0[8], c1[8];
  {
    const float* cp0 = coef + (size_t)(bbase + l31) * RANK + l5 * 8;
    const float* cp1 = coef + (size_t)(bbase + 32 + l31) * RANK + l5 * 8;
    #pragma unroll
    for (int e = 0; e < 8; ++e) { c0[e] = cp0[e]; c1[e] = cp1[e]; }
  }
  const int ib0 = (bbase + l31) * 33, ib1 = (bbase + 32 + l31) * 33;

  // W stage coords (BK=64: 64 rows x 16 float4 = 1024 float4, 2/thread):
  // f in {tid, tid+512}: row = f>>4, c4 = f&15 -> k=c4*4, group g=c4>>1,
  // half=c4&1; frag-major dst shorts = (g*64+row)*8 + half*4.
  const float* wgp0 = W + (size_t)(o0 + (tid >> 4)) * KTOT + kb0 + (tid & 15) * 4;
  const float* wgp1 = wgp0 + (size_t)32 * KTOT;
  const int wd0 = ((((tid & 15) >> 1) * 64 + (tid >> 4)) * 8 + (tid & 1) * 4);
  const int wd1 = wd0 + 32 * 8;

  float4 wA0, wA1, wB0, wB1;    // distance-2 named prefetch sets

  #define SB __builtin_amdgcn_sched_barrier(0);
  #define BARX                                                               \
    SB asm volatile("s_waitcnt lgkmcnt(0)" ::: "memory");                    \
    __builtin_amdgcn_s_barrier(); SB

  #define LOADW(S, P)                                                        \
    { w##S##0 = *(const float4*)(wgp0 + (P) * 64);                           \
      w##S##1 = *(const float4*)(wgp1 + (P) * 64); }

  #define DSW2(S, BUF)                                                       \
    { dsw4pk(&Ws[BUF][wd0], w##S##0); dsw4pk(&Ws[BUF][wd1], w##S##1); }

  #define KSTEP(TL, BUF)                                                     \
    {                                                                        \
      float in0 = in_lds[ib0 + (TL)];                                        \
      float in1 = in_lds[ib1 + (TL)];                                        \
      bf16x8_t af0 = mulcvt8(in0, c0);                                       \
      bf16x8_t af1 = mulcvt8(in1, c1);                                       \
      bf16x8_t bf = *(const bf16x8_t*)                                       \
          &Ws[BUF][((((TL) & 3) * 2 + l5) * 64 + oc * 32 + l31) * 8];        \
      __builtin_amdgcn_s_setprio(1);                                         \
      acc0 = __builtin_amdgcn_mfma_f32_32x32x16_bf16(af0, bf, acc0, 0, 0, 0);\
      acc1 = __builtin_amdgcn_mfma_f32_32x32x16_bf16(af1, bf, acc1, 0, 0, 0);\
      __builtin_amdgcn_s_setprio(0);                                         \
    }

  // phase p: [LOADW(p+2)] ; 4 k-steps from Ws[p&1] ; [DSW(p+1)] ; raw bar
  #define PHASE(P, SC, SN, DOL)                                              \
    if (DOL) { LOADW(SC, (P) + 2) }                                          \
    KSTEP((P) * 4,     (P) & 1)  KSTEP((P) * 4 + 1, (P) & 1)                 \
    KSTEP((P) * 4 + 2, (P) & 1)  KSTEP((P) * 4 + 3, (P) & 1)                 \
    if ((P) + 1 < NPH) { DSW2(SN, ((P) + 1) & 1) }                           \
    BARX

  // ---- prologue B: W phases 0,1 in flight; write phase 0 ----
  LOADW(A, 0)
  LOADW(B, 1)
  DSW2(A, 0)
  BARX

  PHASE(0, A, B, 1)  PHASE(1, B, A, 1)  PHASE(2, A, B, 1)  PHASE(3, B, A, 1)
  PHASE(4, A, B, 1)  PHASE(5, B, A, 1)  PHASE(6, A, B, 0)  PHASE(7, B, A, 0)

  // ---- epilogue: D row(b-part)=(q&3)+8*(q>>2)+4*l5, col(o)=l31 ----
  unsigned short* pp = part + (size_t)kc * (M * NOUT);
  #pragma unroll
  for (int q = 0; q < 16; ++q) {
    int brow = bbase + (q & 3) + 8 * (q >> 2) + 4 * l5;
    int ocol = o0 + oc * 32 + l31;
    pp[(size_t)brow * NOUT + ocol]        = f2bf(acc0[q]);
    pp[(size_t)(brow + 32) * NOUT + ocol] = f2bf(acc1[q]);
  }
  #undef LOADW
  #undef DSW2
  #undef KSTEP
  #undef PHASE
  #undef BARX
  #undef SB
}

// out[b][o] = sum_kc bf2f(part[kc][b][o]) + sum_r bias[o][r]*coef[b][r]
__global__ __launch_bounds__(256) void reduce_bias_kernel(
    const unsigned short* __restrict__ part, const float* __restrict__ bias,
    const float* __restrict__ coef, float* __restrict__ out)
{
  int t = blockIdx.x * 256 + threadIdx.x;
  int idx8 = t * 8;                       // 8 consecutive outputs, same b
  int b = idx8 >> 10, o = idx8 & 1023;

  float s[8];
  #pragma unroll
  for (int j = 0; j < 8; ++j) s[j] = 0.f;

  #pragma unroll
  for (int c = 0; c < NKC; ++c) {
    u16x8_t v = *(const u16x8_t*)(part + (size_t)c * (M * NOUT) + idx8);
    #pragma unroll
    for (int j = 0; j < 8; ++j) s[j] += bf2f(v[j]);
  }

  const f32x4_t* cr = (const f32x4_t*)(coef + (size_t)b * RANK);
  f32x4_t c0 = cr[0], c1 = cr[1], c2 = cr[2], c3 = cr[3];
  #pragma unroll
  for (int j = 0; j < 8; ++j) {
    const f32x4_t* br = (const f32x4_t*)(bias + (size_t)(o + j) * RANK);
    f32x4_t b0 = br[0], b1 = br[1], b2 = br[2], b3 = br[3];
    float bb = 0.f;
    #pragma unroll
    for (int e = 0; e < 4; ++e)
      bb += b0[e] * c0[e] + b1[e] * c1[e] + b2[e] * c2[e] + b3[e] * c3[e];
    s[j] += bb;
  }
  float4* dst = (float4*)(out + idx8);
  dst[0] = make_float4(s[0], s[1], s[2], s[3]);
  dst[1] = make_float4(s[4], s[5], s[6], s[7]);
}

extern "C" void kernel_launch(void* const* d_in, const int* in_sizes, int n_in,
                              void* d_out, int out_size, void* d_ws, size_t ws_size,
                              hipStream_t stream) {
  const float* input = (const float*)d_in[0];   // (256, 1024)
  const float* coef  = (const float*)d_in[1];   // (256, 16)
  const float* W     = (const float*)d_in[2];   // (1024, 1024, 16) -> (1024, 16384)
  const float* bias  = (const float*)d_in[3];   // (1024, 16)
  float* out = (float*)d_out;                   // (256, 1024)

  unsigned short* part = (unsigned short*)d_ws;   // 16 MiB bf16 partials

  gemm_kernel<<<dim3(16, 32), 512, 0, stream>>>(input, coef, W, part);
  reduce_bias_kernel<<<(M * NOUT) / (256 * 8), 256, 0, stream>>>(part, bias, coef, out);
}